// Round 2
// baseline (68.099 us; speedup 1.0000x reference)
//
#include <hip/hip_runtime.h>

// Median 3x3 pooling, reflect padding, (8,16,512,512) f32.
// Each thread: 8 consecutive outputs in a row.
// Column-sort reuse: sort each vertical 3-triple once, combine 3 adjacent
// sorted columns with med3(max3(lo), med3(mid), min3(hi)) — exact median-of-9.

__global__ __launch_bounds__(256) void median3x3_kernel(
        const float* __restrict__ x, float* __restrict__ y) {
    constexpr int H = 512, W = 512;
    constexpr int NWG = 16384;

    // XCD swizzle: 8 XCDs round-robin on dispatch index -> give each XCD a
    // contiguous 2048-block chunk (16 whole planes) for vertical L2 locality.
    const int bid = blockIdx.x;
    const int swz = (bid & 7) * (NWG >> 3) + (bid >> 3);

    const int gid   = swz * 256 + (int)threadIdx.x;
    const int w8    = (gid & 63) << 3;    // 0..504, step 8
    const int h     = (gid >> 6) & 511;
    const int plane = gid >> 15;          // 0..127

    const float* __restrict__ p = x + (size_t)plane * (H * W);

    const int hm = (h == 0)     ? 1     : h - 1;
    const int hp = (h == H - 1) ? H - 2 : h + 1;

    const float* __restrict__ r0 = p + (size_t)hm * W;
    const float* __restrict__ r1 = p + (size_t)h  * W;
    const float* __restrict__ r2 = p + (size_t)hp * W;

    const int wl = (w8 == 0)       ? 1       : w8 - 1;
    const int wr = (w8 == W - 8)   ? W - 2   : w8 + 8;

    const float4 a0 = *reinterpret_cast<const float4*>(r0 + w8);
    const float4 b0 = *reinterpret_cast<const float4*>(r0 + w8 + 4);
    const float4 a1 = *reinterpret_cast<const float4*>(r1 + w8);
    const float4 b1 = *reinterpret_cast<const float4*>(r1 + w8 + 4);
    const float4 a2 = *reinterpret_cast<const float4*>(r2 + w8);
    const float4 b2 = *reinterpret_cast<const float4*>(r2 + w8 + 4);
    const float l0 = r0[wl], l1 = r1[wl], l2 = r2[wl];
    const float R0 = r0[wr], R1 = r1[wr], R2 = r2[wr];

    // 10 columns: -1, 0..7, +8
    float v0[10] = { l0, a0.x, a0.y, a0.z, a0.w, b0.x, b0.y, b0.z, b0.w, R0 };
    float v1[10] = { l1, a1.x, a1.y, a1.z, a1.w, b1.x, b1.y, b1.z, b1.w, R1 };
    float v2[10] = { l2, a2.x, a2.y, a2.z, a2.w, b2.x, b2.y, b2.z, b2.w, R2 };

    float lo[10], mi[10], hi[10];
#pragma unroll
    for (int c = 0; c < 10; ++c) {
        float a = v0[c], b = v1[c], d = v2[c];
        float t;
        t = fminf(a, b); b = fmaxf(a, b); a = t;   // sort a,b
        t = fminf(b, d); d = fmaxf(b, d); b = t;   // sort b,d
        t = fminf(a, b); b = fmaxf(a, b); a = t;   // sort a,b
        lo[c] = a; mi[c] = b; hi[c] = d;
    }

    float out[8];
#pragma unroll
    for (int j = 0; j < 8; ++j) {
        float mx = fmaxf(fmaxf(lo[j], lo[j + 1]), lo[j + 2]);              // v_max3
        float md = __builtin_amdgcn_fmed3f(mi[j], mi[j + 1], mi[j + 2]);   // v_med3
        float mn = fminf(fminf(hi[j], hi[j + 1]), hi[j + 2]);              // v_min3
        out[j] = __builtin_amdgcn_fmed3f(mx, md, mn);
    }

    float* __restrict__ q = y + (size_t)plane * (H * W) + (size_t)h * W + w8;
    *reinterpret_cast<float4*>(q)     = make_float4(out[0], out[1], out[2], out[3]);
    *reinterpret_cast<float4*>(q + 4) = make_float4(out[4], out[5], out[6], out[7]);
}

extern "C" void kernel_launch(void* const* d_in, const int* in_sizes, int n_in,
                              void* d_out, int out_size, void* d_ws, size_t ws_size,
                              hipStream_t stream) {
    const float* x = (const float*)d_in[0];
    float* y = (float*)d_out;
    // 8*16*512*512 / 8 outputs-per-thread = 4,194,304 threads -> 16384 blocks
    median3x3_kernel<<<16384, 256, 0, stream>>>(x, y);
}

// Round 4
// 42.037 us; speedup vs baseline: 1.6200x; 1.6200x over previous
//
#include <hip/hip_runtime.h>

// Median 3x3 pooling, reflect padding, (8,16,512,512) f32.
// One wave per image row (512 floats): lane i computes outputs [4i,4i+4) and
// [256+4i, 256+4i+4). All loads/stores are fully-coalesced float4 (16B lane
// stride); horizontal halos via in-wave shuffles, no extra VMEM.
// Median-of-9 = med3(max3(col_lo), med3(col_mi), min3(col_hi)) on sorted columns.

typedef float f32x4 __attribute__((ext_vector_type(4)));

__device__ __forceinline__ float med3(float a, float b, float c) {
    return __builtin_amdgcn_fmed3f(a, b, c);
}
__device__ __forceinline__ float max3(float a, float b, float c) {
    return fmaxf(fmaxf(a, b), c);
}
__device__ __forceinline__ float min3(float a, float b, float c) {
    return fminf(fminf(a, b), c);
}

#define CSORT(a, b, c) { float _t; \
    _t = fminf(a, b); b = fmaxf(a, b); a = _t; \
    _t = fminf(b, c); c = fmaxf(b, c); b = _t; \
    _t = fminf(a, b); b = fmaxf(a, b); a = _t; }

__global__ __launch_bounds__(256) void median3x3_kernel(
        const float* __restrict__ x, float* __restrict__ y) {
    constexpr int H = 512, W = 512;
    constexpr int NWG = 16384;

    // XCD swizzle: contiguous 2048-block chunk per XCD (16 planes each).
    const int bid  = blockIdx.x;
    const int swz  = (bid & 7) * (NWG >> 3) + (bid >> 3);
    const int lane = (int)threadIdx.x & 63;
    const int wrow = swz * 4 + ((int)threadIdx.x >> 6);  // global row 0..65535
    const int h     = wrow & 511;
    const int plane = wrow >> 9;

    const float* __restrict__ p = x + (size_t)plane * (H * W);
    const int hm = (h == 0)     ? 1     : h - 1;
    const int hp = (h == H - 1) ? H - 2 : h + 1;
    const float* __restrict__ r0 = p + (size_t)hm * W;
    const float* __restrict__ r1 = p + (size_t)h  * W;
    const float* __restrict__ r2 = p + (size_t)hp * W;

    const int wa = lane << 2;          // 0..252
    const int wb = 256 + (lane << 2);  // 256..508

    const f32x4 a0 = *reinterpret_cast<const f32x4*>(r0 + wa);
    const f32x4 b0 = *reinterpret_cast<const f32x4*>(r0 + wb);
    const f32x4 a1 = *reinterpret_cast<const f32x4*>(r1 + wa);
    const f32x4 b1 = *reinterpret_cast<const f32x4*>(r1 + wb);
    const f32x4 a2 = *reinterpret_cast<const f32x4*>(r2 + wa);
    const f32x4 b2 = *reinterpret_cast<const f32x4*>(r2 + wb);

    // Horizontal halos via shuffles. Shuffles hoisted (never under divergence).
    float la0, ra0, lb0, rb0, la1, ra1, lb1, rb1, la2, ra2, lb2, rb2;
#define HALO(a, b, la, ra, lb, rb) { \
    float _lu = __shfl_up((a).w, 1);        /* x[4i-1]       */ \
    float _rd = __shfl_down((a).x, 1);      /* x[4i+4]       */ \
    float _bx = __shfl((b).x, 0);           /* x[256]        */ \
    float _lw = __shfl((a).w, 63);          /* x[255]        */ \
    float _lu2 = __shfl_up((b).w, 1);       /* x[256+4i-1]   */ \
    float _rd2 = __shfl_down((b).x, 1);     /* x[256+4i+4]   */ \
    la = (lane == 0)  ? (a).y : _lu;        /* reflect x[-1]->x[1] */ \
    ra = (lane == 63) ? _bx   : _rd;        /* seam: x[256]        */ \
    lb = (lane == 0)  ? _lw   : _lu2;       /* seam: x[255]        */ \
    rb = (lane == 63) ? (b).z : _rd2;       /* reflect x[512]->x[510] */ }

    HALO(a0, b0, la0, ra0, lb0, rb0)
    HALO(a1, b1, la1, ra1, lb1, rb1)
    HALO(a2, b2, la2, ra2, lb2, rb2)
#undef HALO

    float* __restrict__ q = y + (size_t)plane * (H * W) + (size_t)h * W;

    // ---- group a: columns {la, a.x, a.y, a.z, a.w, ra} ----
    {
        float v0[6] = { la0, a0.x, a0.y, a0.z, a0.w, ra0 };
        float v1[6] = { la1, a1.x, a1.y, a1.z, a1.w, ra1 };
        float v2[6] = { la2, a2.x, a2.y, a2.z, a2.w, ra2 };
        float lo[6], mi[6], hi[6];
#pragma unroll
        for (int c = 0; c < 6; ++c) {
            float A = v0[c], B = v1[c], C = v2[c];
            CSORT(A, B, C);
            lo[c] = A; mi[c] = B; hi[c] = C;
        }
        f32x4 out;
        out.x = med3(max3(lo[0], lo[1], lo[2]), med3(mi[0], mi[1], mi[2]), min3(hi[0], hi[1], hi[2]));
        out.y = med3(max3(lo[1], lo[2], lo[3]), med3(mi[1], mi[2], mi[3]), min3(hi[1], hi[2], hi[3]));
        out.z = med3(max3(lo[2], lo[3], lo[4]), med3(mi[2], mi[3], mi[4]), min3(hi[2], hi[3], hi[4]));
        out.w = med3(max3(lo[3], lo[4], lo[5]), med3(mi[3], mi[4], mi[5]), min3(hi[3], hi[4], hi[5]));
        __builtin_nontemporal_store(out, reinterpret_cast<f32x4*>(q + wa));
    }

    // ---- group b: columns {lb, b.x, b.y, b.z, b.w, rb} ----
    {
        float v0[6] = { lb0, b0.x, b0.y, b0.z, b0.w, rb0 };
        float v1[6] = { lb1, b1.x, b1.y, b1.z, b1.w, rb1 };
        float v2[6] = { lb2, b2.x, b2.y, b2.z, b2.w, rb2 };
        float lo[6], mi[6], hi[6];
#pragma unroll
        for (int c = 0; c < 6; ++c) {
            float A = v0[c], B = v1[c], C = v2[c];
            CSORT(A, B, C);
            lo[c] = A; mi[c] = B; hi[c] = C;
        }
        f32x4 out;
        out.x = med3(max3(lo[0], lo[1], lo[2]), med3(mi[0], mi[1], mi[2]), min3(hi[0], hi[1], hi[2]));
        out.y = med3(max3(lo[1], lo[2], lo[3]), med3(mi[1], mi[2], mi[3]), min3(hi[1], hi[2], hi[3]));
        out.z = med3(max3(lo[2], lo[3], lo[4]), med3(mi[2], mi[3], mi[4]), min3(hi[2], hi[3], hi[4]));
        out.w = med3(max3(lo[3], lo[4], lo[5]), med3(mi[3], mi[4], mi[5]), min3(hi[3], hi[4], hi[5]));
        __builtin_nontemporal_store(out, reinterpret_cast<f32x4*>(q + wb));
    }
}

extern "C" void kernel_launch(void* const* d_in, const int* in_sizes, int n_in,
                              void* d_out, int out_size, void* d_ws, size_t ws_size,
                              hipStream_t stream) {
    const float* x = (const float*)d_in[0];
    float* y = (float*)d_out;
    // 128 planes * 512 rows = 65536 waves -> 16384 blocks of 256 threads
    median3x3_kernel<<<16384, 256, 0, stream>>>(x, y);
}